// Round 6
// baseline (5424.110 us; speedup 1.0000x reference)
//
#include <hip/hip_runtime.h>
#include <hip/hip_bf16.h>

__device__ __forceinline__ float lrelu(float v){ return v >= 0.f ? v : 0.1f*v; }

// Dims: B=4, C=64, H=W=160, HW=25600, per-tensor (B,64,160,160) f32: batch stride 1,638,400 elems
// ws: 4 f32 slots x 26,214,400 B (A, Bv, T1, T2) + part/part2/mu/attv tail. branchH lives in d_out.

// ---------------- spa: per-view 3x3 conv (zero pad at view edges) ----------
__global__ __launch_bounds__(256) void k_spa(const float* __restrict__ buf1, const float* __restrict__ w,
                                             float* __restrict__ out){
  const int b = blockIdx.x / 25, view = blockIdx.x % 25;
  const int bi = view / 5, bj = view % 5;
  const int cog = blockIdx.y;
  const int tid = threadIdx.x;
  __shared__ float plane[34*35];
  __shared__ float wl[144];
  float acc[4][16];
  #pragma unroll
  for (int k=0;k<4;k++)
    #pragma unroll
    for (int c=0;c<16;c++) acc[k][c]=0.f;
  const float* src = buf1 + (size_t)b*1638400 + bi*32*160 + bj*32;
  for (int ci=0; ci<64; ci++){
    __syncthreads();
    for (int idx=tid; idx<34*34; idx+=256){
      int r = idx/34, cc = idx - r*34;
      int si = r-1, sj = cc-1;
      float v = 0.f;
      if ((unsigned)si < 32u && (unsigned)sj < 32u) v = src[(size_t)ci*25600 + si*160 + sj];
      plane[r*35+cc] = v;
    }
    if (tid < 144) wl[tid] = w[((size_t)(cog*16 + tid/9)*64 + ci)*9 + tid%9];
    __syncthreads();
    #pragma unroll
    for (int k=0;k<4;k++){
      int p = tid + k*256;
      int si = p >> 5, sj = p & 31;
      const float* pp = &plane[si*35 + sj];
      float n0=pp[0], n1=pp[1], n2=pp[2];
      float n3=pp[35], n4=pp[36], n5=pp[37];
      float n6=pp[70], n7=pp[71], n8=pp[72];
      #pragma unroll
      for (int c=0;c<16;c++){
        const float* wp = &wl[c*9];
        acc[k][c] += n0*wp[0]+n1*wp[1]+n2*wp[2]+n3*wp[3]+n4*wp[4]+n5*wp[5]+n6*wp[6]+n7*wp[7]+n8*wp[8];
      }
    }
  }
  #pragma unroll
  for (int k=0;k<4;k++){
    int p = tid + k*256;
    int si = p >> 5, sj = p & 31;
    int h = si*5 + bi, wq = sj*5 + bj;
    #pragma unroll
    for (int c=0;c<16;c++){
      int ch = b*64 + cog*16 + c;
      out[(size_t)ch*25600 + h*160 + wq] = lrelu(acc[k][c]);
    }
  }
}

// ---------------- ang: per-macropixel (5x5) 3x3 conv ----------------------
__global__ __launch_bounds__(256) void k_ang(const float* __restrict__ bufA, const float* __restrict__ w,
                                             float* __restrict__ out){
  const int b = blockIdx.x >> 5, mi = blockIdx.x & 31;
  const int cog = blockIdx.y;
  const int tid = threadIdx.x;
  __shared__ float row[800];
  __shared__ float wl[144];
  float acc[4][16];
  #pragma unroll
  for (int k=0;k<4;k++)
    #pragma unroll
    for (int c=0;c<16;c++) acc[k][c]=0.f;
  int pmp[4], pu[4], pv[4];
  bool act[4];
  #pragma unroll
  for (int k=0;k<4;k++){
    int p = tid + k*256;
    act[k] = p < 800;
    int pp = act[k] ? p : 0;
    pmp[k] = pp/25; int pos = pp - pmp[k]*25;
    pu[k] = pos/5; pv[k] = pos - pu[k]*5;
  }
  const float* src = bufA + (size_t)b*1638400 + mi*5*160;
  for (int ci=0; ci<64; ci++){
    __syncthreads();
    for (int idx=tid; idx<800; idx+=256) row[idx] = src[(size_t)ci*25600 + idx];
    if (tid<144) wl[tid] = w[((size_t)(cog*16 + tid/9)*64 + ci)*9 + tid%9];
    __syncthreads();
    #pragma unroll
    for (int k=0;k<4;k++){
      if (act[k]){
        int u = pu[k], v = pv[k], col = pmp[k]*5;
        float n[9];
        #pragma unroll
        for (int dy=0;dy<3;dy++)
          #pragma unroll
          for (int dx=0;dx<3;dx++){
            int uu = u+dy-1, vv = v+dx-1;
            n[dy*3+dx] = ((unsigned)uu<5u && (unsigned)vv<5u) ? row[uu*160 + col + vv] : 0.f;
          }
        #pragma unroll
        for (int c=0;c<16;c++){
          const float* wp=&wl[c*9];
          acc[k][c] += n[0]*wp[0]+n[1]*wp[1]+n[2]*wp[2]+n[3]*wp[3]+n[4]*wp[4]+n[5]*wp[5]+n[6]*wp[6]+n[7]*wp[7]+n[8]*wp[8];
        }
      }
    }
  }
  #pragma unroll
  for (int k=0;k<4;k++){
    if (act[k]){
      int h = mi*5 + pu[k], wq = pmp[k]*5 + pv[k];
      #pragma unroll
      for (int c=0;c<16;c++){
        int ch = b*64 + cog*16 + c;
        out[(size_t)ch*25600 + h*160 + wq] = lrelu(acc[k][c]);
      }
    }
  }
}

// ---------------- fused EPI: [1,15]s5p5 conv + lrelu + 1x1 64->320 + shuffle
template<int VERT>
__global__ __launch_bounds__(320) void k_epi(const float* __restrict__ bufA, const float* __restrict__ we1,
                                             const float* __restrict__ we2, float* __restrict__ out){
  const int b = blockIdx.x / 160, hw = blockIdx.x % 160;
  const int tid = threadIdx.x;
  __shared__ float rowp[64*172];   // per ci: [0,5)=0, data [5,165), [165,172)=0
  __shared__ float y1s[64][32];
  for (int idx=tid; idx<64*160; idx+=320){
    int ci = idx/160, x = idx - ci*160;
    size_t gi = (size_t)b*1638400 + (size_t)ci*25600 + (VERT ? (size_t)x*160 + hw : (size_t)hw*160 + x);
    rowp[ci*172 + 5 + x] = bufA[gi];
  }
  for (int idx=tid; idx<64*12; idx+=320){
    int ci=idx/12, j=idx-ci*12;
    rowp[ci*172 + (j<5 ? j : 160+j)] = 0.f;
  }
  __syncthreads();
  if (tid < 256){
    const int co = tid >> 2, wv0 = (tid & 3)*8;
    float acc[8];
    #pragma unroll
    for (int j=0;j<8;j++) acc[j]=0.f;
    const float* wp0 = we1 + (size_t)co*960;
    for (int ci=0; ci<64; ci++){
      const float* wp = wp0 + ci*15;
      const float* rp = &rowp[ci*172 + wv0*5];
      #pragma unroll
      for (int t=0;t<15;t++){
        float wt = wp[t];
        #pragma unroll
        for (int j=0;j<8;j++) acc[j] += rp[j*5 + t]*wt;
      }
    }
    #pragma unroll
    for (int j=0;j<8;j++) y1s[co][wv0+j] = lrelu(acc[j]);
  }
  __syncthreads();
  const int oc = tid;
  const int kk = oc >> 6, c = oc & 63;
  float a2[32];
  #pragma unroll
  for (int wv=0;wv<32;wv++) a2[wv]=0.f;
  const float* wp = we2 + (size_t)oc*64;
  for (int ci=0; ci<64; ci++){
    float wt = wp[ci];
    const float* yp = &y1s[ci][0];
    #pragma unroll
    for (int wv=0; wv<32; wv++) a2[wv] += yp[wv]*wt;
  }
  if (!VERT){
    float* dst = out + (size_t)(b*64+c)*25600 + hw*160 + kk;
    #pragma unroll
    for (int wv=0; wv<32; wv++) dst[wv*5] = lrelu(a2[wv]);
  } else {
    float* dst = out + (size_t)(b*64+c)*25600 + kk*160 + hw;
    #pragma unroll
    for (int wv=0; wv<32; wv++) dst[wv*800] = lrelu(a2[wv]);
  }
}

// ---------------- pass A: per-branch sums ---------------------------------
__global__ __launch_bounds__(256) void k_redA(const float* __restrict__ b0, const float* __restrict__ b1,
                                              const float* __restrict__ b2, const float* __restrict__ b3,
                                              float* __restrict__ part){
  const int b = blockIdx.y, blk = blockIdx.x;
  const int tid = threadIdx.x;
  const size_t off = (size_t)b*1638400 + (size_t)blk*25600;
  float s0=0,s1=0,s2=0,s3=0;
  for (int it=0; it<100; it++){
    int m = it*256 + tid;
    s0 += b0[off+m]; s1 += b1[off+m]; s2 += b2[off+m]; s3 += b3[off+m];
  }
  float vals[4] = {s0,s1,s2,s3};
  __shared__ float red[4][4];
  int lane = tid & 63, wv = tid >> 6;
  #pragma unroll
  for (int j=0;j<4;j++){
    float v = vals[j];
    #pragma unroll
    for (int o=32;o>0;o>>=1) v += __shfl_down(v,o,64);
    if (lane==0) red[wv][j]=v;
  }
  __syncthreads();
  if (tid<4) part[((size_t)b*64+blk)*16 + tid] = red[0][tid]+red[1][tid]+red[2][tid]+red[3][tid];
}

// ---------------- means ----------------------------------------------------
__global__ void k_mean(const float* __restrict__ part, float* __restrict__ mu){
  const int b = blockIdx.x, tid = threadIdx.x;
  if (tid<4){
    float t=0;
    for (int blk=0;blk<64;blk++) t += part[((size_t)b*64+blk)*16 + tid];
    mu[b*4+tid] = t / 1638400.f;
  }
}

// ---------------- pass B: centered covariance products --------------------
__global__ __launch_bounds__(256) void k_redB(const float* __restrict__ b0, const float* __restrict__ b1,
                                              const float* __restrict__ b2, const float* __restrict__ b3,
                                              const float* __restrict__ mu, float* __restrict__ part2){
  const int b = blockIdx.y, blk = blockIdx.x;
  const int tid = threadIdx.x;
  const size_t off = (size_t)b*1638400 + (size_t)blk*25600;
  const float m0=mu[b*4+0], m1=mu[b*4+1], m2=mu[b*4+2], m3=mu[b*4+3];
  float p00=0,p01=0,p02=0,p03=0,p11=0,p12=0,p13=0,p22=0,p23=0,p33=0;
  for (int it=0; it<100; it++){
    int m = it*256 + tid;
    float x0 = b0[off+m]-m0;
    float x1 = b1[off+m]-m1;
    float x2 = b2[off+m]-m2;
    float x3 = b3[off+m]-m3;
    p00+=x0*x0; p01+=x0*x1; p02+=x0*x2; p03+=x0*x3;
    p11+=x1*x1; p12+=x1*x2; p13+=x1*x3;
    p22+=x2*x2; p23+=x2*x3; p33+=x3*x3;
  }
  float vals[10] = {p00,p01,p02,p03,p11,p12,p13,p22,p23,p33};
  __shared__ float red[4][10];
  int lane = tid & 63, wv = tid >> 6;
  #pragma unroll
  for (int j=0;j<10;j++){
    float v = vals[j];
    #pragma unroll
    for (int o=32;o>0;o>>=1) v += __shfl_down(v,o,64);
    if (lane==0) red[wv][j]=v;
  }
  __syncthreads();
  if (tid<10) part2[((size_t)b*64+blk)*16 + tid] = red[0][tid]+red[1][tid]+red[2][tid]+red[3][tid];
}

// ---------------- attention coefficients (literal) ------------------------
__global__ void k_att2(const float* __restrict__ part2,
        const float* __restrict__ alpha, const float* __restrict__ gamma, const float* __restrict__ beta,
        int iblk, float* __restrict__ attv){
  const int b = blockIdx.x, tid = threadIdx.x;
  __shared__ float st[10];
  if (tid<10){
    float t=0;
    for (int blk=0;blk<64;blk++) t += part2[((size_t)b*64+blk)*16 + tid];
    st[tid]=t;
  }
  __syncthreads();
  if (tid==0){
    const float M = 1638400.f;
    float S[4][4];
    S[0][0]=st[0]; S[0][1]=S[1][0]=st[1]; S[0][2]=S[2][0]=st[2]; S[0][3]=S[3][0]=st[3];
    S[1][1]=st[4]; S[1][2]=S[2][1]=st[5]; S[1][3]=S[3][1]=st[6];
    S[2][2]=st[7]; S[2][3]=S[3][2]=st[8]; S[3][3]=st[9];
    float al=alpha[iblk], ga=gamma[iblk], be=beta[iblk];
    float scale = al/(M-1.f);
    float cov[4][4], ss=0.f;
    for (int n=0;n<4;n++) for (int k=0;k<4;k++){
      float c = S[n][k]*scale;
      cov[n][k]=c; ss += c*c;
    }
    float rms = sqrtf(ss/16.f + 1e-5f);
    for (int n=0;n<4;n++) for (int k=0;k<4;k++){
      float g = ga*cov[n][k]/rms + be;
      attv[b*16 + n*4+k] = g/(1.f+expf(-g));   // g*sigmoid(g)
    }
  }
}

// ---------------- literal attention mix: out_n = x_n + sum_k att[n,k] x_k --
__global__ __launch_bounds__(256) void k_mix(float* b0, float* b1, float* b2, float* b3,
                                             const float* __restrict__ attv){
  const int b = blockIdx.y;
  const size_t m = (size_t)b*1638400 + blockIdx.x*256 + threadIdx.x;
  float a[16];
  #pragma unroll
  for (int j=0;j<16;j++) a[j] = attv[b*16+j];
  float x0=b0[m], x1=b1[m], x2=b2[m], x3=b3[m];
  float y0 = x0 + a[0]*x0 + a[1]*x1 + a[2]*x2 + a[3]*x3;
  float y1 = x1 + a[4]*x0 + a[5]*x1 + a[6]*x2 + a[7]*x3;
  float y2 = x2 + a[8]*x0 + a[9]*x1 + a[10]*x2 + a[11]*x3;
  float y3 = x3 + a[12]*x0 + a[13]*x1 + a[14]*x2 + a[15]*x3;
  b0[m]=y0; b1[m]=y1; b2[m]=y2; b3[m]=y3;
}

// ---------------- fuse1: literal conv1x1 256->64 with wf1, lrelu ----------
__global__ __launch_bounds__(256) void k_fuse1L(const float* b0, const float* __restrict__ b1,
                                                const float* __restrict__ b2, const float* __restrict__ b3,
                                                const float* __restrict__ wf1, float* y64){
  const int tile = blockIdx.x, b = blockIdx.y;
  const int px0 = tile*64;
  const int tid = threadIdx.x;
  const int ti = tid >> 4, tj = tid & 15;
  __shared__ float xs[64][65];
  __shared__ float wsh[64][65];
  float acc[4][4];
  #pragma unroll
  for (int i=0;i<4;i++)
    #pragma unroll
    for (int j=0;j<4;j++) acc[i][j]=0.f;
  const float* bptr[4] = {b0,b1,b2,b3};
  for (int kb=0; kb<4; kb++){
    const float* xbk = bptr[kb] + (size_t)b*1638400 + px0;
    __syncthreads();
    for (int idx=tid; idx<4096; idx+=256){
      int kc=idx>>6, px=idx&63;
      xs[kc][px] = xbk[(size_t)kc*25600 + px];
    }
    for (int idx=tid; idx<4096; idx+=256){
      int co=idx>>6, k2=idx&63;
      wsh[co][k2] = wf1[co*256 + kb*64 + k2];
    }
    __syncthreads();
    for (int k2=0;k2<64;k2++){
      float a0=wsh[ti][k2], a1=wsh[ti+16][k2], a2=wsh[ti+32][k2], a3=wsh[ti+48][k2];
      float v0=xs[k2][tj], v1=xs[k2][tj+16], v2=xs[k2][tj+32], v3=xs[k2][tj+48];
      acc[0][0]+=a0*v0; acc[0][1]+=a0*v1; acc[0][2]+=a0*v2; acc[0][3]+=a0*v3;
      acc[1][0]+=a1*v0; acc[1][1]+=a1*v1; acc[1][2]+=a1*v2; acc[1][3]+=a1*v3;
      acc[2][0]+=a2*v0; acc[2][1]+=a2*v1; acc[2][2]+=a2*v2; acc[2][3]+=a2*v3;
      acc[3][0]+=a3*v0; acc[3][1]+=a3*v1; acc[3][2]+=a3*v2; acc[3][3]+=a3*v3;
    }
  }
  #pragma unroll
  for (int ii=0;ii<4;ii++)
    #pragma unroll
    for (int jj=0;jj<4;jj++){
      int co = ti + ii*16, px = tj + jj*16;
      y64[((size_t)b*64+co)*25600 + px0 + px] = lrelu(acc[ii][jj]);
    }
}

// ---------------- fuse2: dilated 3x3 (dil 5, pad 5) + residual + mac2sai --
// Reference _mac2sai (literal): in (B,C,160,160) -> reshape (B,C,5,32,5,32)
// [H=a_i*32+hh, W=a_j*32+ww] -> transpose to (B,C,hh,ww,a_i,a_j) -> flat reshape (B,C,160,160).
// flat idx = hh*800 + ww*25 + a_i*5 + a_j  (NOT the pairwise interleave!)
template<int FINAL>
__global__ __launch_bounds__(256) void k_fuse2(const float* __restrict__ y64, const float* resid,
                                               const float* __restrict__ w, float* outA,
                                               float* outB1, float* dout){
  const int b = blockIdx.x / 25, tile = blockIdx.x % 25;
  const int th0 = (tile/5)*32, tw0 = (tile%5)*32;
  const int cog = blockIdx.y;
  const int tid = threadIdx.x;
  __shared__ float plane[42*43];
  __shared__ float wl[144];
  float acc[4][16];
  #pragma unroll
  for (int k=0;k<4;k++)
    #pragma unroll
    for (int c=0;c<16;c++) acc[k][c]=0.f;
  const float* src = y64 + (size_t)b*1638400;
  for (int ci=0; ci<64; ci++){
    __syncthreads();
    for (int idx=tid; idx<42*42; idx+=256){
      int r = idx/42, cc = idx - r*42;
      int gh = th0 + r - 5, gw = tw0 + cc - 5;
      float v = 0.f;
      if ((unsigned)gh < 160u && (unsigned)gw < 160u) v = src[(size_t)ci*25600 + gh*160 + gw];
      plane[r*43+cc] = v;
    }
    if (tid<144) wl[tid] = w[((size_t)(cog*16 + tid/9)*64 + ci)*9 + tid%9];
    __syncthreads();
    #pragma unroll
    for (int k=0;k<4;k++){
      int p = tid + k*256;
      int si = p >> 5, sj = p & 31;
      const float* pp = &plane[si*43 + sj];
      float n0=pp[0],   n1=pp[5],    n2=pp[10];
      float n3=pp[215], n4=pp[220],  n5=pp[225];
      float n6=pp[430], n7=pp[435],  n8=pp[440];
      #pragma unroll
      for (int c=0;c<16;c++){
        const float* wp=&wl[c*9];
        acc[k][c] += n0*wp[0]+n1*wp[1]+n2*wp[2]+n3*wp[3]+n4*wp[4]+n5*wp[5]+n6*wp[6]+n7*wp[7]+n8*wp[8];
      }
    }
  }
  #pragma unroll
  for (int k=0;k<4;k++){
    int p = tid + k*256;
    int si = p >> 5, sj = p & 31;
    int h = th0 + si, wq = tw0 + sj;
    #pragma unroll
    for (int c=0;c<16;c++){
      int cg = cog*16 + c;
      size_t base = ((size_t)(b*64+cg)*160 + h)*160 + wq;
      float v = acc[k][c] + resid[base];
      if (FINAL){
        dout[base] = v;
      } else {
        outA[base] = v;
        // reference-literal mac2sai: flat = hh*800 + ww*25 + a_i*5 + a_j
        // with a_i = h>>5, hh = h&31, a_j = wq>>5, ww = wq&31
        size_t m2s = (size_t)(b*64+cg)*25600 + (size_t)(h&31)*800 + (wq&31)*25 + (h>>5)*5 + (wq>>5);
        outB1[m2s] = v;
      }
    }
  }
}

extern "C" void kernel_launch(void* const* d_in, const int* in_sizes, int n_in,
                              void* d_out, int out_size, void* d_ws, size_t ws_size,
                              hipStream_t stream){
  const float* x    = (const float*)d_in[0];
  const float* x1   = (const float*)d_in[1];
  const float* wspa = (const float*)d_in[2];
  const float* wang = (const float*)d_in[3];
  const float* we1  = (const float*)d_in[4];
  const float* we2  = (const float*)d_in[5];
  const float* al   = (const float*)d_in[6];
  const float* ga   = (const float*)d_in[7];
  const float* be   = (const float*)d_in[8];
  const float* wf1  = (const float*)d_in[9];
  const float* wf2  = (const float*)d_in[10];

  char* ws = (char*)d_ws;
  const size_t SLOT = 26214400;
  float* A  = (float*)(ws);          // MacPI buf (in-place residual chain)
  float* Bv = (float*)(ws +   SLOT); // SAI buf / branchV (rotates with T2)
  float* T1 = (float*)(ws + 2*SLOT); // branchSpa, then y64 in-place
  float* T2 = (float*)(ws + 3*SLOT); // branchAng, then newB1
  float* part  = (float*)(ws + 4*SLOT);            // 4*64*16 f32
  float* part2 = (float*)(ws + 4*SLOT + 16384);    // 4*64*16 f32
  float* mu    = (float*)(ws + 4*SLOT + 32768);    // 16 f32
  float* attv  = (float*)(ws + 4*SLOT + 32832);    // 64 f32
  float* D = (float*)d_out;          // branchH scratch; final output at the end

  for (int i=0;i<4;i++){
    const float* Asrc  = (i==0) ? x  : (const float*)A;
    const float* B1src = (i==0) ? x1 : (const float*)Bv;
    k_spa<<<dim3(100,4),256,0,stream>>>(B1src, wspa + (size_t)i*36864, T1);
    k_ang<<<dim3(128,4),256,0,stream>>>(Asrc,  wang + (size_t)i*36864, T2);
    k_epi<0><<<640,320,0,stream>>>(Asrc, we1 + (size_t)i*61440, we2 + (size_t)i*20480, D);
    k_epi<1><<<640,320,0,stream>>>(Asrc, we1 + (size_t)i*61440, we2 + (size_t)i*20480, Bv);
    k_redA<<<dim3(64,4),256,0,stream>>>(T1, T2, D, Bv, part);
    k_mean<<<4,64,0,stream>>>(part, mu);
    k_redB<<<dim3(64,4),256,0,stream>>>(T1, T2, D, Bv, mu, part2);
    k_att2<<<4,64,0,stream>>>(part2, al, ga, be, i, attv);
    k_mix<<<dim3(6400,4),256,0,stream>>>(T1, T2, D, Bv, attv);
    k_fuse1L<<<dim3(400,4),256,0,stream>>>(T1, T2, D, Bv, wf1 + (size_t)i*16384, T1);
    if (i<3){
      k_fuse2<0><<<dim3(100,4),256,0,stream>>>(T1, Asrc, wf2 + (size_t)i*36864, A, T2, nullptr);
      float* t = Bv; Bv = T2; T2 = t;
    } else {
      k_fuse2<1><<<dim3(100,4),256,0,stream>>>(T1, Asrc, wf2 + (size_t)i*36864, nullptr, nullptr, D);
    }
  }
}